// Round 7
// baseline (56.942 us; speedup 1.0000x reference)
//
#include <hip/hip_runtime.h>
#include <hip/hip_bf16.h>
#include <math.h>

#define T_DIM 32
#define B_DIM 128
#define D_DIM 512
#define M_DIM 1024

constexpr float DT = 0.1875f;            // 3.0 / 16

typedef __attribute__((ext_vector_type(8))) short bf16x8;   // 8 bf16 = 4 VGPR
typedef __attribute__((ext_vector_type(4))) float f32x4;    // MFMA acc
typedef __attribute__((ext_vector_type(2))) float f32x2;    // packed (cos,sin)

__device__ __forceinline__ ushort f2bf(float f) {           // RNE fp32->bf16
    unsigned u = __float_as_uint(f);
    u += 0x7FFFu + ((u >> 16) & 1u);
    return (ushort)(u >> 16);
}

// v_sin/v_cos take REVOLUTIONS (ISA: D=sin(S0*2pi)); reduce with floor.
__device__ __forceinline__ void fast_sincos(float theta, float& s, float& c) {
    constexpr float INV_2PI = 0.15915494309189535f;
    float r = theta * INV_2PI;
    r -= floorf(r);
    s = __builtin_amdgcn_sinf(r);
    c = __builtin_amdgcn_cosf(r);
}

// ---------- K1: prep. blocks 0..63: A colnorm + transpose -> ant (bf16, [m][d]).
//                blocks 64..319: z fp32 -> bf16 copy. ----------
__global__ __launch_bounds__(256) void prep_kernel(const float* __restrict__ A,
                                                   const float* __restrict__ z,
                                                   ushort* __restrict__ zb,
                                                   ushort* __restrict__ ant) {
    const int bid = blockIdx.x;
    const int tid = threadIdx.x;

    if (bid >= 64) {                       // ---- zconv: 256 blocks x 8192 floats ----
        const size_t base = (size_t)(bid - 64) * 8192 + tid * 8;
#pragma unroll
        for (int j = 0; j < 4; ++j) {
            const size_t i = base + j * 2048;
            const float4 a = *reinterpret_cast<const float4*>(&z[i]);
            const float4 b = *reinterpret_cast<const float4*>(&z[i + 4]);
            uint4 p;
            p.x = (unsigned)f2bf(a.x) | ((unsigned)f2bf(a.y) << 16);
            p.y = (unsigned)f2bf(a.z) | ((unsigned)f2bf(a.w) << 16);
            p.z = (unsigned)f2bf(b.x) | ((unsigned)f2bf(b.y) << 16);
            p.w = (unsigned)f2bf(b.z) | ((unsigned)f2bf(b.w) << 16);
            *reinterpret_cast<uint4*>(&zb[i]) = p;
        }
        return;
    }

    // ---- norm + transpose for 16 m-columns ----
    __shared__ float red[256];
    __shared__ float inv[16];
    __shared__ float tile[128][17];

    const int mB = bid * 16;
    const int mo = tid & 15;
    const int dg = tid >> 4;               // 16 groups of 32 d
    float ss = 0.0f;
#pragma unroll 4
    for (int i = 0; i < 32; ++i) {
        const float v = A[(size_t)(dg * 32 + i) * M_DIM + mB + mo];
        ss = fmaf(v, v, ss);
    }
    red[tid] = ss;
    __syncthreads();
    for (int s = 128; s >= 16; s >>= 1) {
        if (tid < s) red[tid] += red[tid + s];
        __syncthreads();
    }
    if (tid < 16) inv[tid] = 1.0f / fmaxf(sqrtf(red[tid]), 1e-12f);

#pragma unroll
    for (int ch = 0; ch < 4; ++ch) {       // 4 chunks of 128 d
        const int dB = ch * 128;
#pragma unroll
        for (int q = 0; q < 2; ++q) {
            const int s  = tid + 256 * q;  // 0..511
            const int r  = s >> 2;         // 0..127
            const int c4 = (s & 3) * 4;    // 0,4,8,12
            const float4 v = *reinterpret_cast<const float4*>(
                &A[(size_t)(dB + r) * M_DIM + mB + c4]);
            tile[r][c4]     = v.x;
            tile[r][c4 + 1] = v.y;
            tile[r][c4 + 2] = v.z;
            tile[r][c4 + 3] = v.w;
        }
        __syncthreads();
        {
            const int m  = tid >> 4;       // 0..15
            const int d8 = (tid & 15) * 8; // 0..120
            const float sc = inv[m];
            uint4 p;
            p.x = (unsigned)f2bf(tile[d8 + 0][m] * sc) | ((unsigned)f2bf(tile[d8 + 1][m] * sc) << 16);
            p.y = (unsigned)f2bf(tile[d8 + 2][m] * sc) | ((unsigned)f2bf(tile[d8 + 3][m] * sc) << 16);
            p.z = (unsigned)f2bf(tile[d8 + 4][m] * sc) | ((unsigned)f2bf(tile[d8 + 5][m] * sc) << 16);
            p.w = (unsigned)f2bf(tile[d8 + 6][m] * sc) | ((unsigned)f2bf(tile[d8 + 7][m] * sc) << 16);
            *reinterpret_cast<uint4*>(&ant[(size_t)(mB + m) * D_DIM + dB + d8]) = p;
        }
        __syncthreads();
    }
}

// ---------- K2: fused bf16-MFMA GEMM + CF statistic ----------
// 256 thr (4 waves: 2 b-row halves x 2 m-col halves), tile 128 b x 32 m, K=512, BK=64.
// sched_barrier(0) after each value's Chebyshev chain keeps live ranges small
// (without it the -O3 scheduler interleaves all 16 chains -> spill; R2-R5 evidence).
#define CHEB(CS) { const f32x2 nxt = c2 * cur - prev; prev = cur; cur = nxt; CS += cur; }
#define CF_ONE(V) { \
    float s1, c1; fast_sincos((V) * DT, s1, c1); \
    const float c2 = 2.0f * c1; \
    f32x2 prev = {1.0f, 0.0f}; \
    f32x2 cur  = {c1, s1}; \
    cs0 += cur; \
    CHEB(cs1)  CHEB(cs2)  CHEB(cs3)  CHEB(cs4)  CHEB(cs5) \
    CHEB(cs6)  CHEB(cs7)  CHEB(cs8)  CHEB(cs9)  CHEB(cs10) \
    CHEB(cs11) CHEB(cs12) CHEB(cs13) CHEB(cs14) CHEB(cs15) \
    __builtin_amdgcn_sched_barrier(0); }
#define RED(CS) { \
    CS.x += __shfl_xor(CS.x, 16); CS.x += __shfl_xor(CS.x, 32); \
    CS.y += __shfl_xor(CS.y, 16); CS.y += __shfl_xor(CS.y, 32); }
#define ST(CS, K) { wred[wc][l15][K] = CS.x; wred[wc][l15][16 + K] = CS.y; }
#define FIN(CS, KK) { \
    constexpr float tk = DT * (float)(KK); \
    const float g  = __expf(-0.5f * tk * tk); \
    const float w  = (((KK) == 16) ? DT : 2.0f * DT) * g; \
    const float totC = wred[wc][l15][(KK) - 1]      + CS.x; \
    const float totS = wred[wc][l15][16 + (KK) - 1] + CS.y; \
    const float cm = fmaf(totC, invB, -g); \
    const float sm = totS * invB; \
    s = fmaf(w, fmaf(cm, cm, sm * sm), s); }

__global__ __launch_bounds__(256, 4) void fused_kernel(const ushort* __restrict__ zb,
                                                       const ushort* __restrict__ ant,
                                                       float* __restrict__ partials) {
    __shared__ __align__(16) ushort As[128][72];    // +16B pad per row (2-way max)
    __shared__ __align__(16) ushort Bs[32][72];
    __shared__ float wred[2][16][33];               // [wc][col][k | 16+k], padded
    __shared__ float bred[2];

    const int tid  = threadIdx.x;
    const int mB   = blockIdx.x * 32;               // 32 m-blocks share one zb t-slice
    const int t    = blockIdx.y;                    // 0..31
    const int wave = tid >> 6;
    const int lane = tid & 63;
    const int wr   = wave >> 1;                     // b-row half
    const int wc   = wave & 1;                      // m-col half
    const int l15  = lane & 15;
    const int lhi  = lane >> 4;

    const ushort* zrow = zb + (size_t)t * B_DIM * D_DIM;

    const int ar0 = tid >> 3;            // A rows tid/8 + 32q
    const int ac  = (tid & 7) * 8;
    const int br0 = tid >> 3;            // B rows 0..31
    const int bc  = (tid & 7) * 8;

    f32x4 acc[4];
#pragma unroll
    for (int fm = 0; fm < 4; ++fm) acc[fm] = (f32x4)(0.0f);

    uint4 aReg[4], bReg;
#pragma unroll
    for (int q = 0; q < 4; ++q)
        aReg[q] = *reinterpret_cast<const uint4*>(&zrow[(size_t)(ar0 + 32 * q) * D_DIM + ac]);
    bReg = *reinterpret_cast<const uint4*>(&ant[(size_t)(mB + br0) * D_DIM + bc]);

#pragma unroll
    for (int it = 0; it < 8; ++it) {
        __syncthreads();
#pragma unroll
        for (int q = 0; q < 4; ++q)
            *reinterpret_cast<uint4*>(&As[ar0 + 32 * q][ac]) = aReg[q];
        *reinterpret_cast<uint4*>(&Bs[br0][bc]) = bReg;
        __syncthreads();

        if (it < 7) {                               // prefetch next K-tile
            const int k0 = (it + 1) * 64;
#pragma unroll
            for (int q = 0; q < 4; ++q)
                aReg[q] = *reinterpret_cast<const uint4*>(&zrow[(size_t)(ar0 + 32 * q) * D_DIM + k0 + ac]);
            bReg = *reinterpret_cast<const uint4*>(&ant[(size_t)(mB + br0) * D_DIM + k0 + bc]);
        }

#pragma unroll
        for (int ks = 0; ks < 2; ++ks) {
            const bf16x8 bfrag = *reinterpret_cast<const bf16x8*>(&Bs[wc * 16 + l15][ks * 32 + lhi * 8]);
#pragma unroll
            for (int fm = 0; fm < 4; ++fm) {
                const bf16x8 afrag = *reinterpret_cast<const bf16x8*>(&As[wr * 64 + fm * 16 + l15][ks * 32 + lhi * 8]);
                acc[fm] = __builtin_amdgcn_mfma_f32_16x16x32_bf16(afrag, bfrag, acc[fm], 0, 0, 0);
            }
        }
    }

    // ---- CF accumulation into 16 named f32x2 registers, one value at a time ----
    f32x2 cs0  = {0.f, 0.f}, cs1  = {0.f, 0.f}, cs2  = {0.f, 0.f}, cs3  = {0.f, 0.f};
    f32x2 cs4  = {0.f, 0.f}, cs5  = {0.f, 0.f}, cs6  = {0.f, 0.f}, cs7  = {0.f, 0.f};
    f32x2 cs8  = {0.f, 0.f}, cs9  = {0.f, 0.f}, cs10 = {0.f, 0.f}, cs11 = {0.f, 0.f};
    f32x2 cs12 = {0.f, 0.f}, cs13 = {0.f, 0.f}, cs14 = {0.f, 0.f}, cs15 = {0.f, 0.f};

    __builtin_amdgcn_sched_barrier(0);
#pragma unroll
    for (int fm = 0; fm < 4; ++fm) {
        const f32x4 av = acc[fm];
        CF_ONE(av.x) CF_ONE(av.y) CF_ONE(av.z) CF_ONE(av.w)
    }

    // reduce over the wave's 64 b-rows (4 lhi lane-groups)
    RED(cs0)  RED(cs1)  RED(cs2)  RED(cs3)  RED(cs4)  RED(cs5)  RED(cs6)  RED(cs7)
    RED(cs8)  RED(cs9)  RED(cs10) RED(cs11) RED(cs12) RED(cs13) RED(cs14) RED(cs15)

    if (wr == 0 && lane < 16) {
        ST(cs0, 0)   ST(cs1, 1)   ST(cs2, 2)   ST(cs3, 3)
        ST(cs4, 4)   ST(cs5, 5)   ST(cs6, 6)   ST(cs7, 7)
        ST(cs8, 8)   ST(cs9, 9)   ST(cs10, 10) ST(cs11, 11)
        ST(cs12, 12) ST(cs13, 13) ST(cs14, 14) ST(cs15, 15)
    }
    __syncthreads();

    if (wr == 1) {
        const float invB = 1.0f / 128.0f;
        float s = 0.0f;
        FIN(cs0, 1)   FIN(cs1, 2)   FIN(cs2, 3)   FIN(cs3, 4)
        FIN(cs4, 5)   FIN(cs5, 6)   FIN(cs6, 7)   FIN(cs7, 8)
        FIN(cs8, 9)   FIN(cs9, 10)  FIN(cs10, 11) FIN(cs11, 12)
        FIN(cs12, 13) FIN(cs13, 14) FIN(cs14, 15) FIN(cs15, 16)
        // butterfly over all 64 lanes: each col counted 4x (lhi copies)
#pragma unroll
        for (int m = 1; m < 64; m <<= 1) s += __shfl_xor(s, m);
        if (lane == 0) bred[wc] = s;
    }
    __syncthreads();
    if (tid == 0)
        partials[blockIdx.y * 32 + blockIdx.x] = (bred[0] + bred[1]) * 0.25f * 128.0f;
}

// ---------- K3: final reduce of 1024 partials ----------
__global__ __launch_bounds__(256) void finalize_kernel(const float* __restrict__ partials,
                                                       float* __restrict__ out) {
    __shared__ float red[256];
    const int tid = threadIdx.x;
    red[tid] = partials[tid] + partials[tid + 256] + partials[tid + 512] + partials[tid + 768];
    __syncthreads();
    for (int s = 128; s > 0; s >>= 1) {
        if (tid < s) red[tid] += red[tid + s];
        __syncthreads();
    }
    if (tid == 0) out[0] = red[0] * (1.0f / (float)(T_DIM * M_DIM));
}

extern "C" void kernel_launch(void* const* d_in, const int* in_sizes, int n_in,
                              void* d_out, int out_size, void* d_ws, size_t ws_size,
                              hipStream_t stream) {
    const float* z = (const float*)d_in[0];   // (32,128,512)
    const float* A = (const float*)d_in[1];   // (512,1024)
    float* out = (float*)d_out;

    char* ws = (char*)d_ws;
    ushort* zb       = (ushort*)ws;                               // 4 MB
    ushort* ant      = (ushort*)(ws + 4 * 1024 * 1024);           // 1 MB
    float*  partials = (float*)(ws + 5 * 1024 * 1024);            // 4 KB

    prep_kernel<<<320, 256, 0, stream>>>(A, z, zb, ant);
    fused_kernel<<<dim3(M_DIM / 32, T_DIM), 256, 0, stream>>>(zb, ant, partials);
    finalize_kernel<<<1, 256, 0, stream>>>(partials, out);
}